// Round 1
// baseline (256.511 us; speedup 1.0000x reference)
//
#include <hip/hip_runtime.h>

// Problem: B=D=H=512. Inputs (fp32): x[512,512], W1[512,512], b1[512],
// W2[512,512], b2[512], w3[512], b3[1].
// Outputs: out[512] then gram[512,512] concatenated in d_out (fp32).
//
// Gramian decomposition (derived from per-sample vjp):
//   g2_i = w3 ⊙ 1{z2_i>0};  g1_i = (W2 g2_i) ⊙ 1{z1_i>0}
//   G = 1 + H2 H2^T + (1 + H1 H1^T) ⊙ (G2 G2^T) + (1 + X X^T) ⊙ (G1 G1^T)

#define NN 512

// ---------------- GEMM: C = relu(A@B + bias), 512x512, row-major ----------
__global__ __launch_bounds__(256) void gemm_bias_relu(
    const float* __restrict__ A, const float* __restrict__ Bm,
    const float* __restrict__ bias, float* __restrict__ C) {
    __shared__ float As[16][64];   // transposed A tile: As[k][i]
    __shared__ float Bs[16][64];   // Bs[k][j]
    const int tid = threadIdx.x;
    const int tx = tid & 15, ty = tid >> 4;
    const int i0 = blockIdx.y * 64, j0 = blockIdx.x * 64;
    const int lrow = tid >> 2;           // 0..63
    const int lk4  = (tid & 3) * 4;      // 0,4,8,12
    const int brow = tid >> 4;           // 0..15
    const int bj4  = (tid & 15) * 4;     // 0..60
    float acc[4][4] = {};
    for (int k0 = 0; k0 < NN; k0 += 16) {
        float4 av = *(const float4*)&A [(i0 + lrow) * NN + k0 + lk4];
        float4 bv = *(const float4*)&Bm[(k0 + brow) * NN + j0 + bj4];
        __syncthreads();
        As[lk4 + 0][lrow] = av.x; As[lk4 + 1][lrow] = av.y;
        As[lk4 + 2][lrow] = av.z; As[lk4 + 3][lrow] = av.w;
        *(float4*)&Bs[brow][bj4] = bv;
        __syncthreads();
        #pragma unroll
        for (int k = 0; k < 16; ++k) {
            float4 a4 = *(const float4*)&As[k][ty * 4];
            float4 b4 = *(const float4*)&Bs[k][tx * 4];
            float a[4] = {a4.x, a4.y, a4.z, a4.w};
            float b[4] = {b4.x, b4.y, b4.z, b4.w};
            #pragma unroll
            for (int ii = 0; ii < 4; ++ii)
                #pragma unroll
                for (int jj = 0; jj < 4; ++jj)
                    acc[ii][jj] += a[ii] * b[jj];
        }
    }
    #pragma unroll
    for (int ii = 0; ii < 4; ++ii) {
        const int i = i0 + ty * 4 + ii;
        #pragma unroll
        for (int jj = 0; jj < 4; ++jj) {
            const int j = j0 + tx * 4 + jj;
            float v = acc[ii][jj] + bias[j];
            C[i * NN + j] = v > 0.f ? v : 0.f;
        }
    }
}

// ------------- out[i] = H2[i,:]·w3 + b3;  G2[i,j] = (H2[i,j]>0)?w3[j]:0 ----
__global__ __launch_bounds__(256) void out_g2_kernel(
    const float* __restrict__ H2, const float* __restrict__ w3,
    const float* __restrict__ b3, float* __restrict__ out,
    float* __restrict__ G2) {
    const int i = blockIdx.x;
    const int t = threadIdx.x;
    float s = 0.f;
    #pragma unroll
    for (int j = t; j < NN; j += 256) {
        float h = H2[i * NN + j];
        float w = w3[j];
        s += h * w;
        G2[i * NN + j] = (h > 0.f) ? w : 0.f;
    }
    #pragma unroll
    for (int off = 32; off > 0; off >>= 1) s += __shfl_down(s, off, 64);
    __shared__ float partial[4];
    if ((t & 63) == 0) partial[t >> 6] = s;
    __syncthreads();
    if (t == 0) out[i] = partial[0] + partial[1] + partial[2] + partial[3] + b3[0];
}

// ------ G1[i,c] = (H1[i,c]>0) * sum_j G2[i,j]*W2[c,j]   (A @ W^T, masked) --
__global__ __launch_bounds__(256) void gemm_abt_mask(
    const float* __restrict__ A,    // G2
    const float* __restrict__ W,    // W2 (rows used as B^T)
    const float* __restrict__ Mref, // H1 (mask source)
    float* __restrict__ C) {        // G1
    __shared__ float As[16][64];    // As[j][i]
    __shared__ float Ws[16][64];    // Ws[j][c]
    const int tid = threadIdx.x;
    const int tx = tid & 15, ty = tid >> 4;
    const int i0 = blockIdx.y * 64, c0 = blockIdx.x * 64;
    const int lrow = tid >> 2;
    const int lj4  = (tid & 3) * 4;
    float acc[4][4] = {};
    for (int jb = 0; jb < NN; jb += 16) {
        float4 av = *(const float4*)&A[(i0 + lrow) * NN + jb + lj4];
        float4 wv = *(const float4*)&W[(c0 + lrow) * NN + jb + lj4];
        __syncthreads();
        As[lj4 + 0][lrow] = av.x; As[lj4 + 1][lrow] = av.y;
        As[lj4 + 2][lrow] = av.z; As[lj4 + 3][lrow] = av.w;
        Ws[lj4 + 0][lrow] = wv.x; Ws[lj4 + 1][lrow] = wv.y;
        Ws[lj4 + 2][lrow] = wv.z; Ws[lj4 + 3][lrow] = wv.w;
        __syncthreads();
        #pragma unroll
        for (int j = 0; j < 16; ++j) {
            float4 a4 = *(const float4*)&As[j][ty * 4];
            float4 b4 = *(const float4*)&Ws[j][tx * 4];
            float a[4] = {a4.x, a4.y, a4.z, a4.w};
            float b[4] = {b4.x, b4.y, b4.z, b4.w};
            #pragma unroll
            for (int ii = 0; ii < 4; ++ii)
                #pragma unroll
                for (int jj = 0; jj < 4; ++jj)
                    acc[ii][jj] += a[ii] * b[jj];
        }
    }
    #pragma unroll
    for (int ii = 0; ii < 4; ++ii) {
        const int i = i0 + ty * 4 + ii;
        #pragma unroll
        for (int jj = 0; jj < 4; ++jj) {
            const int c = c0 + tx * 4 + jj;
            C[i * NN + c] = (Mref[i * NN + c] > 0.f) ? acc[ii][jj] : 0.f;
        }
    }
}

// ---- Fused Gramian: 5 syrk accumulators per 64x64 tile, then combine -----
__global__ __launch_bounds__(256) void gram_kernel(
    const float* __restrict__ X,  const float* __restrict__ H1,
    const float* __restrict__ G1, const float* __restrict__ H2,
    const float* __restrict__ G2, float* __restrict__ gram) {
    __shared__ float Si[5][16][64];  // i-side tiles, transposed [k][i]
    __shared__ float Sj[5][16][64];  // j-side tiles, transposed [k][j]
    const int tid = threadIdx.x;
    const int tx = tid & 15, ty = tid >> 4;
    const int i0 = blockIdx.y * 64, j0 = blockIdx.x * 64;
    const int lrow = tid >> 2;
    const int lk4  = (tid & 3) * 4;
    const float* Z[5] = {X, H1, G1, H2, G2};
    float acc[5][4][4] = {};
    for (int k0 = 0; k0 < NN; k0 += 16) {
        float4 vi[5], vj[5];
        #pragma unroll
        for (int m = 0; m < 5; ++m) {
            vi[m] = *(const float4*)&Z[m][(i0 + lrow) * NN + k0 + lk4];
            vj[m] = *(const float4*)&Z[m][(j0 + lrow) * NN + k0 + lk4];
        }
        __syncthreads();
        #pragma unroll
        for (int m = 0; m < 5; ++m) {
            Si[m][lk4 + 0][lrow] = vi[m].x; Si[m][lk4 + 1][lrow] = vi[m].y;
            Si[m][lk4 + 2][lrow] = vi[m].z; Si[m][lk4 + 3][lrow] = vi[m].w;
            Sj[m][lk4 + 0][lrow] = vj[m].x; Sj[m][lk4 + 1][lrow] = vj[m].y;
            Sj[m][lk4 + 2][lrow] = vj[m].z; Sj[m][lk4 + 3][lrow] = vj[m].w;
        }
        __syncthreads();
        #pragma unroll
        for (int k = 0; k < 16; ++k) {
            #pragma unroll
            for (int m = 0; m < 5; ++m) {
                float4 a4 = *(const float4*)&Si[m][k][ty * 4];
                float4 b4 = *(const float4*)&Sj[m][k][tx * 4];
                float a[4] = {a4.x, a4.y, a4.z, a4.w};
                float b[4] = {b4.x, b4.y, b4.z, b4.w};
                #pragma unroll
                for (int ii = 0; ii < 4; ++ii)
                    #pragma unroll
                    for (int jj = 0; jj < 4; ++jj)
                        acc[m][ii][jj] += a[ii] * b[jj];
            }
        }
    }
    #pragma unroll
    for (int ii = 0; ii < 4; ++ii) {
        const int i = i0 + ty * 4 + ii;
        #pragma unroll
        for (int jj = 0; jj < 4; ++jj) {
            const int j = j0 + tx * 4 + jj;
            // G = 1 + H2H2T + G2G2T*(1+H1H1T) + G1G1T*(1+XXT)
            float g = 1.f + acc[3][ii][jj]
                    + acc[4][ii][jj] * (1.f + acc[1][ii][jj])
                    + acc[2][ii][jj] * (1.f + acc[0][ii][jj]);
            gram[i * NN + j] = g;
        }
    }
}

extern "C" void kernel_launch(void* const* d_in, const int* in_sizes, int n_in,
                              void* d_out, int out_size, void* d_ws, size_t ws_size,
                              hipStream_t stream) {
    const float* x  = (const float*)d_in[0];
    const float* W1 = (const float*)d_in[1];
    const float* b1 = (const float*)d_in[2];
    const float* W2 = (const float*)d_in[3];
    const float* b2 = (const float*)d_in[4];
    const float* w3 = (const float*)d_in[5];
    const float* b3 = (const float*)d_in[6];

    float* out  = (float*)d_out;       // [512]
    float* gram = out + NN;            // [512*512]

    float* H1 = (float*)d_ws;          // 1 MB each
    float* H2 = H1 + NN * NN;
    float* G2 = H2 + NN * NN;
    float* G1 = G2 + NN * NN;

    dim3 grid(8, 8), blk(256);
    gemm_bias_relu<<<grid, blk, 0, stream>>>(x,  W1, b1, H1);
    gemm_bias_relu<<<grid, blk, 0, stream>>>(H1, W2, b2, H2);
    out_g2_kernel <<<dim3(NN), blk, 0, stream>>>(H2, w3, b3, out, G2);
    gemm_abt_mask <<<grid, blk, 0, stream>>>(G2, W2, H1, G1);
    gram_kernel   <<<grid, blk, 0, stream>>>(x, H1, G1, H2, G2, gram);
}

// Round 3
// 125.917 us; speedup vs baseline: 2.0371x; 2.0371x over previous
//
#include <hip/hip_runtime.h>
#include <hip/hip_bf16.h>

// B=D=H=512. Inputs fp32: x, W1, b1, W2, b2, w3, b3.
// out[512] ++ gram[512,512] in d_out.
// G = 1 + H2H2^T + (1+H1H1^T)⊙(G2G2^T) + (1+XX^T)⊙(G1G1^T)
//   g2 = w3⊙1{z2>0};  g1 = (W2 g2)⊙1{z1>0}
// Forward GEMMs fp32 (exact masks + exact `out`); all syrks/G1 in bf16 MFMA.

#define NN 512

typedef __attribute__((ext_vector_type(8))) short v8s;
typedef __attribute__((ext_vector_type(4))) float v4f;

static __device__ __forceinline__ unsigned short f2bf(float f) {
    union { float f; unsigned u; } v; v.f = f;
    unsigned r = v.u + 0x7FFF + ((v.u >> 16) & 1);
    return (unsigned short)(r >> 16);
}

// ---- prep: xb=bf16(x), W2b=bf16(W2), out[i]=b3[0] ------------------------
__global__ __launch_bounds__(256) void prep(
    const float* __restrict__ x, const float* __restrict__ W2,
    const float* __restrict__ b3,
    unsigned short* __restrict__ xb, unsigned short* __restrict__ W2b,
    float* __restrict__ out) {
    const int idx = (blockIdx.x * 256 + threadIdx.x) * 4;  // grid 256 -> 262144
    float4 xv = *(const float4*)&x[idx];
    float4 wv = *(const float4*)&W2[idx];
    ushort4 xo, wo;
    xo.x = f2bf(xv.x); xo.y = f2bf(xv.y); xo.z = f2bf(xv.z); xo.w = f2bf(xv.w);
    wo.x = f2bf(wv.x); wo.y = f2bf(wv.y); wo.z = f2bf(wv.z); wo.w = f2bf(wv.w);
    *(ushort4*)&xb[idx] = xo;
    *(ushort4*)&W2b[idx] = wo;
    if (blockIdx.x == 0) {
        float b = b3[0];
        out[threadIdx.x] = b;
        out[threadIdx.x + 256] = b;
    }
}

// ---- fwd1: H1 = relu(x@W1 + b1) fp32; also H1b ---------------------------
__global__ __launch_bounds__(256) void fwd1(
    const float* __restrict__ X, const float* __restrict__ W1,
    const float* __restrict__ b1,
    float* __restrict__ H1, unsigned short* __restrict__ H1b) {
    __shared__ float As[32][34];   // As[k][i] (transposed), pad 34 -> 8B align
    __shared__ float Bs[32][34];   // Bs[k][j]
    const int t = threadIdx.x;
    const int tx = t & 15, ty = t >> 4;
    const int i0 = blockIdx.y * 32, j0 = blockIdx.x * 32;
    const int lr = t >> 3;          // 0..31
    const int lk = (t & 7) * 4;     // 0..28
    float acc[2][2] = {};
    for (int k0 = 0; k0 < NN; k0 += 32) {
        float4 av = *(const float4*)&X [(i0 + lr) * NN + k0 + lk];
        float4 bv = *(const float4*)&W1[(k0 + lr) * NN + j0 + lk];
        __syncthreads();
        As[lk + 0][lr] = av.x; As[lk + 1][lr] = av.y;
        As[lk + 2][lr] = av.z; As[lk + 3][lr] = av.w;
        Bs[lr][lk + 0] = bv.x; Bs[lr][lk + 1] = bv.y;
        Bs[lr][lk + 2] = bv.z; Bs[lr][lk + 3] = bv.w;
        __syncthreads();
        #pragma unroll
        for (int k = 0; k < 32; ++k) {
            float2 a2 = *(const float2*)&As[k][2 * ty];
            float2 b2 = *(const float2*)&Bs[k][2 * tx];
            acc[0][0] += a2.x * b2.x; acc[0][1] += a2.x * b2.y;
            acc[1][0] += a2.y * b2.x; acc[1][1] += a2.y * b2.y;
        }
    }
    #pragma unroll
    for (int ii = 0; ii < 2; ++ii) {
        const int i = i0 + 2 * ty + ii;
        #pragma unroll
        for (int jj = 0; jj < 2; ++jj) {
            const int j = j0 + 2 * tx + jj;
            float v = acc[ii][jj] + b1[j];
            float h = v > 0.f ? v : 0.f;
            H1[i * NN + j] = h;
            H1b[i * NN + j] = f2bf(h);
        }
    }
}

// ---- fwd2: z2 = H1@W2 + b2; H2b, G2b, out += H2·w3 -----------------------
__global__ __launch_bounds__(256) void fwd2(
    const float* __restrict__ H1, const float* __restrict__ W2,
    const float* __restrict__ b2, const float* __restrict__ w3,
    unsigned short* __restrict__ H2b, unsigned short* __restrict__ G2b,
    float* __restrict__ out) {
    __shared__ float As[32][34];
    __shared__ float Bs[32][34];
    __shared__ float rsum[32];
    const int t = threadIdx.x;
    const int tx = t & 15, ty = t >> 4;
    const int i0 = blockIdx.y * 32, j0 = blockIdx.x * 32;
    const int lr = t >> 3;
    const int lk = (t & 7) * 4;
    if (t < 32) rsum[t] = 0.f;
    float acc[2][2] = {};
    for (int k0 = 0; k0 < NN; k0 += 32) {
        float4 av = *(const float4*)&H1[(i0 + lr) * NN + k0 + lk];
        float4 bv = *(const float4*)&W2[(k0 + lr) * NN + j0 + lk];
        __syncthreads();
        As[lk + 0][lr] = av.x; As[lk + 1][lr] = av.y;
        As[lk + 2][lr] = av.z; As[lk + 3][lr] = av.w;
        Bs[lr][lk + 0] = bv.x; Bs[lr][lk + 1] = bv.y;
        Bs[lr][lk + 2] = bv.z; Bs[lr][lk + 3] = bv.w;
        __syncthreads();
        #pragma unroll
        for (int k = 0; k < 32; ++k) {
            float2 a2 = *(const float2*)&As[k][2 * ty];
            float2 b2v = *(const float2*)&Bs[k][2 * tx];
            acc[0][0] += a2.x * b2v.x; acc[0][1] += a2.x * b2v.y;
            acc[1][0] += a2.y * b2v.x; acc[1][1] += a2.y * b2v.y;
        }
    }
    float w3v[2], bias[2];
    #pragma unroll
    for (int jj = 0; jj < 2; ++jj) {
        w3v[jj]  = w3[j0 + 2 * tx + jj];
        bias[jj] = b2[j0 + 2 * tx + jj];
    }
    float rowc[2] = {0.f, 0.f};
    #pragma unroll
    for (int ii = 0; ii < 2; ++ii) {
        const int i = i0 + 2 * ty + ii;
        #pragma unroll
        for (int jj = 0; jj < 2; ++jj) {
            const int j = j0 + 2 * tx + jj;
            float z = acc[ii][jj] + bias[jj];
            float h = z > 0.f ? z : 0.f;
            H2b[i * NN + j] = f2bf(h);
            G2b[i * NN + j] = (z > 0.f) ? f2bf(w3v[jj]) : (unsigned short)0;
            rowc[ii] += h * w3v[jj];
        }
    }
    #pragma unroll
    for (int ii = 0; ii < 2; ++ii)
        atomicAdd(&rsum[2 * ty + ii], rowc[ii]);
    __syncthreads();
    if (t < 32) atomicAdd(&out[i0 + t], rsum[t]);
}

// ---- g1: G1b[i,c] = 1{H1>0} * (G2b @ W2b^T), bf16 MFMA, no LDS -----------
__global__ __launch_bounds__(256) void g1k(
    const unsigned short* __restrict__ G2b, const unsigned short* __restrict__ W2b,
    const float* __restrict__ H1, unsigned short* __restrict__ G1b) {
    const int t = threadIdx.x;
    const int wave = t >> 6, lane = t & 63;
    const int r = lane & 15, quad = lane >> 4;
    const int i0 = blockIdx.y * 32 + 16 * (wave >> 1);
    const int c0 = blockIdx.x * 32 + 16 * (wave & 1);
    const unsigned short* arow = G2b + (i0 + r) * NN + quad * 8;
    const unsigned short* brow = W2b + (c0 + r) * NN + quad * 8;
    v4f acc = {0.f, 0.f, 0.f, 0.f};
    #pragma unroll
    for (int k0 = 0; k0 < NN; k0 += 32) {
        v8s a = *(const v8s*)(arow + k0);
        v8s b = *(const v8s*)(brow + k0);
        acc = __builtin_amdgcn_mfma_f32_16x16x32_bf16(a, b, acc, 0, 0, 0);
    }
    // C/D: col = lane&15, row = quad*4 + reg  [m89-verified]
    #pragma unroll
    for (int rr = 0; rr < 4; ++rr) {
        const int i = i0 + quad * 4 + rr;
        const int c = c0 + r;
        float v = (H1[i * NN + c] > 0.f) ? acc[rr] : 0.f;
        G1b[i * NN + c] = f2bf(v);
    }
}

// ---- gram: 5 bf16 syrks fused, no LDS ------------------------------------
__global__ __launch_bounds__(256) void gramk(
    const unsigned short* __restrict__ Xb, const unsigned short* __restrict__ H1b,
    const unsigned short* __restrict__ G1b, const unsigned short* __restrict__ H2b,
    const unsigned short* __restrict__ G2b, float* __restrict__ gram) {
    const int t = threadIdx.x;
    const int wave = t >> 6, lane = t & 63;
    const int r = lane & 15, quad = lane >> 4;
    const int i0 = blockIdx.y * 32 + 16 * (wave >> 1);
    const int j0 = blockIdx.x * 32 + 16 * (wave & 1);
    const int ao = (i0 + r) * NN + quad * 8;
    const int bo = (j0 + r) * NN + quad * 8;
    v4f a0 = {0.f,0.f,0.f,0.f}, a1 = a0, a2 = a0, a3 = a0, a4 = a0;
    #pragma unroll
    for (int k0 = 0; k0 < NN; k0 += 32) {
        v8s xa = *(const v8s*)(Xb  + ao + k0), xb2 = *(const v8s*)(Xb  + bo + k0);
        v8s ha = *(const v8s*)(H1b + ao + k0), hb  = *(const v8s*)(H1b + bo + k0);
        v8s ga = *(const v8s*)(G1b + ao + k0), gb  = *(const v8s*)(G1b + bo + k0);
        v8s ua = *(const v8s*)(H2b + ao + k0), ub  = *(const v8s*)(H2b + bo + k0);
        v8s va = *(const v8s*)(G2b + ao + k0), vb  = *(const v8s*)(G2b + bo + k0);
        a0 = __builtin_amdgcn_mfma_f32_16x16x32_bf16(xa, xb2, a0, 0, 0, 0);
        a1 = __builtin_amdgcn_mfma_f32_16x16x32_bf16(ha, hb,  a1, 0, 0, 0);
        a2 = __builtin_amdgcn_mfma_f32_16x16x32_bf16(ga, gb,  a2, 0, 0, 0);
        a3 = __builtin_amdgcn_mfma_f32_16x16x32_bf16(ua, ub,  a3, 0, 0, 0);
        a4 = __builtin_amdgcn_mfma_f32_16x16x32_bf16(va, vb,  a4, 0, 0, 0);
    }
    #pragma unroll
    for (int rr = 0; rr < 4; ++rr) {
        const int i = i0 + quad * 4 + rr;
        const int j = j0 + r;
        float g = 1.f + a3[rr] + a4[rr] * (1.f + a1[rr]) + a2[rr] * (1.f + a0[rr]);
        gram[i * NN + j] = g;
    }
}

extern "C" void kernel_launch(void* const* d_in, const int* in_sizes, int n_in,
                              void* d_out, int out_size, void* d_ws, size_t ws_size,
                              hipStream_t stream) {
    const float* x  = (const float*)d_in[0];
    const float* W1 = (const float*)d_in[1];
    const float* b1 = (const float*)d_in[2];
    const float* W2 = (const float*)d_in[3];
    const float* b2 = (const float*)d_in[4];
    const float* w3 = (const float*)d_in[5];
    const float* b3 = (const float*)d_in[6];

    float* out  = (float*)d_out;
    float* gram = out + NN;

    // ws: H1 fp32 (1MB) + 6 bf16 matrices (512KB each) = 4MB
    float* H1           = (float*)d_ws;
    unsigned short* xb  = (unsigned short*)(H1 + NN * NN);
    unsigned short* W2b = xb  + NN * NN;
    unsigned short* H1b = W2b + NN * NN;
    unsigned short* H2b = H1b + NN * NN;
    unsigned short* G2b = H2b + NN * NN;
    unsigned short* G1b = G2b + NN * NN;

    dim3 blk(256);
    prep<<<dim3(256), blk, 0, stream>>>(x, W2, b3, xb, W2b, out);
    fwd1<<<dim3(16, 16), blk, 0, stream>>>(x, W1, b1, H1, H1b);
    fwd2<<<dim3(16, 16), blk, 0, stream>>>(H1, W2, b2, w3, H2b, G2b, out);
    g1k <<<dim3(16, 16), blk, 0, stream>>>(G2b, W2b, H1, G1b);
    gramk<<<dim3(16, 16), blk, 0, stream>>>(xb, H1b, G1b, H2b, G2b, gram);
}

// Round 4
// 114.672 us; speedup vs baseline: 2.2369x; 1.0981x over previous
//
#include <hip/hip_runtime.h>

// B=D=H=512. Inputs fp32: x, W1, b1, W2, b2, w3, b3.
// d_out = out[512] ++ gram[512,512] (fp32).
// G = 1 + H2H2^T + (1+H1H1^T)⊙(G2G2^T) + (1+XX^T)⊙(G1G1^T)
//   g2 = w3⊙1{z2>0};  g1 = (W2 g2)⊙1{z1>0}
// Forward GEMMs via split-bf16 MFMA (hi+lo, 3 products -> ~1e-5 abs error);
// syrks and G1 in plain bf16 MFMA. No LDS in any K-loop.

#define NN 512

typedef __attribute__((ext_vector_type(8))) short v8s;
typedef __attribute__((ext_vector_type(4))) float v4f;

static __device__ __forceinline__ unsigned short f2bf(float f) {
    union { float f; unsigned u; } v; v.f = f;
    unsigned r = v.u + 0x7FFF + ((v.u >> 16) & 1);
    return (unsigned short)(r >> 16);
}
static __device__ __forceinline__ float bf2f(unsigned short h) {
    union { unsigned u; float f; } v; v.u = ((unsigned)h) << 16;
    return v.f;
}

// ---- prep: z=0: W1 transpose+split; z=1: W2 transpose+split + plain W2b;
//            z=2: x straight split + out[i]=b3 ------------------------------
__global__ __launch_bounds__(256) void prep(
    const float* __restrict__ x, const float* __restrict__ W1,
    const float* __restrict__ W2, const float* __restrict__ b3,
    unsigned short* __restrict__ xhi, unsigned short* __restrict__ xlo,
    unsigned short* __restrict__ W1th, unsigned short* __restrict__ W1tl,
    unsigned short* __restrict__ W2th, unsigned short* __restrict__ W2tl,
    unsigned short* __restrict__ W2b, float* __restrict__ out) {
    __shared__ float T[32][33];
    const int t = threadIdx.x;
    const int lr = t >> 3, lc = (t & 7) * 4;
    const int r0 = blockIdx.y * 32, c0 = blockIdx.x * 32;
    const int z = blockIdx.z;
    if (z == 2) {
        float4 v = *(const float4*)&x[(r0 + lr) * NN + c0 + lc];
        ushort4 hi, lo;
        hi.x = f2bf(v.x); lo.x = f2bf(v.x - bf2f(hi.x));
        hi.y = f2bf(v.y); lo.y = f2bf(v.y - bf2f(hi.y));
        hi.z = f2bf(v.z); lo.z = f2bf(v.z - bf2f(hi.z));
        hi.w = f2bf(v.w); lo.w = f2bf(v.w - bf2f(hi.w));
        *(ushort4*)&xhi[(r0 + lr) * NN + c0 + lc] = hi;
        *(ushort4*)&xlo[(r0 + lr) * NN + c0 + lc] = lo;
        if (blockIdx.x == 0 && t < 32) out[r0 + t] = b3[0];
        return;
    }
    const float* src = (z == 1) ? W2 : W1;
    float4 v = *(const float4*)&src[(r0 + lr) * NN + c0 + lc];
    if (z == 1) {
        ushort4 h;
        h.x = f2bf(v.x); h.y = f2bf(v.y); h.z = f2bf(v.z); h.w = f2bf(v.w);
        *(ushort4*)&W2b[(r0 + lr) * NN + c0 + lc] = h;
    }
    T[lr][lc + 0] = v.x; T[lr][lc + 1] = v.y;
    T[lr][lc + 2] = v.z; T[lr][lc + 3] = v.w;
    __syncthreads();
    unsigned short* dh = (z == 1) ? W2th : W1th;
    unsigned short* dl = (z == 1) ? W2tl : W1tl;
    float a0 = T[lc + 0][lr], a1 = T[lc + 1][lr];
    float a2 = T[lc + 2][lr], a3 = T[lc + 3][lr];
    ushort4 hi, lo;
    hi.x = f2bf(a0); lo.x = f2bf(a0 - bf2f(hi.x));
    hi.y = f2bf(a1); lo.y = f2bf(a1 - bf2f(hi.y));
    hi.z = f2bf(a2); lo.z = f2bf(a2 - bf2f(hi.z));
    hi.w = f2bf(a3); lo.w = f2bf(a3 - bf2f(hi.w));
    *(ushort4*)&dh[(c0 + lr) * NN + r0 + lc] = hi;
    *(ushort4*)&dl[(c0 + lr) * NN + r0 + lc] = lo;
}

// ---- fwd1: h = relu(x@W1+b1) via split-bf16 MFMA; writes hi/lo of h ------
__global__ __launch_bounds__(256) void fwd1(
    const unsigned short* __restrict__ Ahi, const unsigned short* __restrict__ Alo,
    const unsigned short* __restrict__ Bhi, const unsigned short* __restrict__ Blo,
    const float* __restrict__ bias,
    unsigned short* __restrict__ Chi, unsigned short* __restrict__ Clo) {
    const int t = threadIdx.x;
    const int wave = t >> 6, lane = t & 63;
    const int r = lane & 15, quad = lane >> 4;
    const int i0 = blockIdx.y * 32 + 16 * (wave >> 1);
    const int j0 = blockIdx.x * 32 + 16 * (wave & 1);
    const int ao = (i0 + r) * NN + quad * 8;
    const int bo = (j0 + r) * NN + quad * 8;
    v4f hh = {0.f, 0.f, 0.f, 0.f}, lh = hh, hl = hh;
    #pragma unroll
    for (int k0 = 0; k0 < NN; k0 += 32) {
        v8s ah = *(const v8s*)(Ahi + ao + k0);
        v8s al = *(const v8s*)(Alo + ao + k0);
        v8s bh = *(const v8s*)(Bhi + bo + k0);
        v8s bl = *(const v8s*)(Blo + bo + k0);
        hh = __builtin_amdgcn_mfma_f32_16x16x32_bf16(ah, bh, hh, 0, 0, 0);
        lh = __builtin_amdgcn_mfma_f32_16x16x32_bf16(al, bh, lh, 0, 0, 0);
        hl = __builtin_amdgcn_mfma_f32_16x16x32_bf16(ah, bl, hl, 0, 0, 0);
    }
    const float bj = bias[j0 + r];
    #pragma unroll
    for (int rr = 0; rr < 4; ++rr) {
        const int i = i0 + quad * 4 + rr, j = j0 + r;
        float zv = (hh[rr] + lh[rr]) + hl[rr] + bj;
        float h = zv > 0.f ? zv : 0.f;
        unsigned short hi = f2bf(h);
        Chi[i * NN + j] = hi;
        Clo[i * NN + j] = f2bf(h - bf2f(hi));
    }
}

// ---- fwd2: z2 = H1@W2+b2; writes H2b, G2b, out += h2·w3 ------------------
__global__ __launch_bounds__(256) void fwd2(
    const unsigned short* __restrict__ Ahi, const unsigned short* __restrict__ Alo,
    const unsigned short* __restrict__ Bhi, const unsigned short* __restrict__ Blo,
    const float* __restrict__ b2, const float* __restrict__ w3,
    unsigned short* __restrict__ H2b, unsigned short* __restrict__ G2b,
    float* __restrict__ out) {
    const int t = threadIdx.x;
    const int wave = t >> 6, lane = t & 63;
    const int r = lane & 15, quad = lane >> 4;
    const int i0 = blockIdx.y * 32 + 16 * (wave >> 1);
    const int j0 = blockIdx.x * 32 + 16 * (wave & 1);
    const int ao = (i0 + r) * NN + quad * 8;
    const int bo = (j0 + r) * NN + quad * 8;
    v4f hh = {0.f, 0.f, 0.f, 0.f}, lh = hh, hl = hh;
    #pragma unroll
    for (int k0 = 0; k0 < NN; k0 += 32) {
        v8s ah = *(const v8s*)(Ahi + ao + k0);
        v8s al = *(const v8s*)(Alo + ao + k0);
        v8s bh = *(const v8s*)(Bhi + bo + k0);
        v8s bl = *(const v8s*)(Blo + bo + k0);
        hh = __builtin_amdgcn_mfma_f32_16x16x32_bf16(ah, bh, hh, 0, 0, 0);
        lh = __builtin_amdgcn_mfma_f32_16x16x32_bf16(al, bh, lh, 0, 0, 0);
        hl = __builtin_amdgcn_mfma_f32_16x16x32_bf16(ah, bl, hl, 0, 0, 0);
    }
    const float bj = b2[j0 + r];
    const float wj = w3[j0 + r];
    const unsigned short wjb = f2bf(wj);
    #pragma unroll
    for (int rr = 0; rr < 4; ++rr) {
        const int i = i0 + quad * 4 + rr, j = j0 + r;
        float zv = (hh[rr] + lh[rr]) + hl[rr] + bj;
        float h = zv > 0.f ? zv : 0.f;
        H2b[i * NN + j] = f2bf(h);
        G2b[i * NN + j] = (zv > 0.f) ? wjb : (unsigned short)0;
        float p = h * wj;
        p += __shfl_xor(p, 1, 64);
        p += __shfl_xor(p, 2, 64);
        p += __shfl_xor(p, 4, 64);
        p += __shfl_xor(p, 8, 64);
        if (r == 0) atomicAdd(&out[i], p);
    }
}

// ---- g1: G1b[i,c] = 1{H1>0} * (G2b @ W2^T), bf16 MFMA --------------------
__global__ __launch_bounds__(256) void g1k(
    const unsigned short* __restrict__ G2b, const unsigned short* __restrict__ W2b,
    const unsigned short* __restrict__ H1b, unsigned short* __restrict__ G1b) {
    const int t = threadIdx.x;
    const int wave = t >> 6, lane = t & 63;
    const int r = lane & 15, quad = lane >> 4;
    const int i0 = blockIdx.y * 32 + 16 * (wave >> 1);
    const int c0 = blockIdx.x * 32 + 16 * (wave & 1);
    const unsigned short* arow = G2b + (i0 + r) * NN + quad * 8;
    const unsigned short* brow = W2b + (c0 + r) * NN + quad * 8;
    v4f acc = {0.f, 0.f, 0.f, 0.f};
    #pragma unroll
    for (int k0 = 0; k0 < NN; k0 += 32) {
        v8s a = *(const v8s*)(arow + k0);
        v8s b = *(const v8s*)(brow + k0);
        acc = __builtin_amdgcn_mfma_f32_16x16x32_bf16(a, b, acc, 0, 0, 0);
    }
    #pragma unroll
    for (int rr = 0; rr < 4; ++rr) {
        const int i = i0 + quad * 4 + rr;
        const int c = c0 + r;
        // h >= 0, bf16(h) > 0 iff h > 0 (up to denormal cutoff)
        float v = (H1b[i * NN + c] != 0) ? acc[rr] : 0.f;
        G1b[i * NN + c] = f2bf(v);
    }
}

// ---- gram: 5 bf16 syrks fused, no LDS ------------------------------------
__global__ __launch_bounds__(256) void gramk(
    const unsigned short* __restrict__ Xb, const unsigned short* __restrict__ H1b,
    const unsigned short* __restrict__ G1b, const unsigned short* __restrict__ H2b,
    const unsigned short* __restrict__ G2b, float* __restrict__ gram) {
    const int t = threadIdx.x;
    const int wave = t >> 6, lane = t & 63;
    const int r = lane & 15, quad = lane >> 4;
    const int i0 = blockIdx.y * 32 + 16 * (wave >> 1);
    const int j0 = blockIdx.x * 32 + 16 * (wave & 1);
    const int ao = (i0 + r) * NN + quad * 8;
    const int bo = (j0 + r) * NN + quad * 8;
    v4f a0 = {0.f,0.f,0.f,0.f}, a1 = a0, a2 = a0, a3 = a0, a4 = a0;
    #pragma unroll
    for (int k0 = 0; k0 < NN; k0 += 32) {
        v8s xa = *(const v8s*)(Xb  + ao + k0), xb2 = *(const v8s*)(Xb  + bo + k0);
        v8s ha = *(const v8s*)(H1b + ao + k0), hb  = *(const v8s*)(H1b + bo + k0);
        v8s ga = *(const v8s*)(G1b + ao + k0), gb  = *(const v8s*)(G1b + bo + k0);
        v8s ua = *(const v8s*)(H2b + ao + k0), ub  = *(const v8s*)(H2b + bo + k0);
        v8s va = *(const v8s*)(G2b + ao + k0), vb  = *(const v8s*)(G2b + bo + k0);
        a0 = __builtin_amdgcn_mfma_f32_16x16x32_bf16(xa, xb2, a0, 0, 0, 0);
        a1 = __builtin_amdgcn_mfma_f32_16x16x32_bf16(ha, hb,  a1, 0, 0, 0);
        a2 = __builtin_amdgcn_mfma_f32_16x16x32_bf16(ga, gb,  a2, 0, 0, 0);
        a3 = __builtin_amdgcn_mfma_f32_16x16x32_bf16(ua, ub,  a3, 0, 0, 0);
        a4 = __builtin_amdgcn_mfma_f32_16x16x32_bf16(va, vb,  a4, 0, 0, 0);
    }
    #pragma unroll
    for (int rr = 0; rr < 4; ++rr) {
        const int i = i0 + quad * 4 + rr;
        const int j = j0 + r;
        float g = 1.f + a3[rr] + a4[rr] * (1.f + a1[rr]) + a2[rr] * (1.f + a0[rr]);
        gram[i * NN + j] = g;
    }
}

extern "C" void kernel_launch(void* const* d_in, const int* in_sizes, int n_in,
                              void* d_out, int out_size, void* d_ws, size_t ws_size,
                              hipStream_t stream) {
    const float* x  = (const float*)d_in[0];
    const float* W1 = (const float*)d_in[1];
    const float* b1 = (const float*)d_in[2];
    const float* W2 = (const float*)d_in[3];
    const float* b2 = (const float*)d_in[4];
    const float* w3 = (const float*)d_in[5];
    const float* b3 = (const float*)d_in[6];

    float* out  = (float*)d_out;
    float* gram = out + NN;

    // 12 bf16 [512][512] arrays, 512 KB each = 6 MB total
    unsigned short* p    = (unsigned short*)d_ws;
    unsigned short* xhi  = p;  p += NN * NN;
    unsigned short* xlo  = p;  p += NN * NN;
    unsigned short* W1th = p;  p += NN * NN;
    unsigned short* W1tl = p;  p += NN * NN;
    unsigned short* W2th = p;  p += NN * NN;
    unsigned short* W2tl = p;  p += NN * NN;
    unsigned short* W2b  = p;  p += NN * NN;
    unsigned short* H1b  = p;  p += NN * NN;
    unsigned short* H1lo = p;  p += NN * NN;
    unsigned short* H2b  = p;  p += NN * NN;
    unsigned short* G2b  = p;  p += NN * NN;
    unsigned short* G1b  = p;  p += NN * NN;

    dim3 blk(256);
    prep <<<dim3(16, 16, 3), blk, 0, stream>>>(x, W1, W2, b3, xhi, xlo,
                                               W1th, W1tl, W2th, W2tl, W2b, out);
    fwd1 <<<dim3(16, 16), blk, 0, stream>>>(xhi, xlo, W1th, W1tl, b1, H1b, H1lo);
    fwd2 <<<dim3(16, 16), blk, 0, stream>>>(H1b, H1lo, W2th, W2tl, b2, w3,
                                            H2b, G2b, out);
    g1k  <<<dim3(16, 16), blk, 0, stream>>>(G2b, W2b, H1b, G1b);
    gramk<<<dim3(16, 16), blk, 0, stream>>>(xhi, H1b, G1b, H2b, G2b, gram);
}